// Round 1
// baseline (4856.463 us; speedup 1.0000x reference)
//
#include <hip/hip_runtime.h>
#include <cstdint>
#include <cstddef>

// ---------------------------------------------------------------------------
// SplitLayer: scatter -> GEMM+BN+ReLU -> scatter -> two BN-MLPs.
// Round 0: correct fp32 baseline. GEMMs are 64x128-tile vector-ALU kernels
// with fused input transforms; BN stats via separate column-reduce passes.
// ---------------------------------------------------------------------------

__device__ __forceinline__ void atomAddF(float* p, float v) {
  unsafeAtomicAdd(p, v);  // global_atomic_add_f32, agent scope
}

// ---- scatter 1: lift_aggr[dst[i]] += node_rep[src[i]] ----------------------
__global__ __launch_bounds__(256) void k_scatter1(
    const float* __restrict__ node, const int* __restrict__ src,
    const int* __restrict__ dst, float* __restrict__ lift, int M) {
  int t = blockIdx.x * blockDim.x + threadIdx.x;
  int i = t >> 5;
  if (i >= M) return;
  int c = (t & 31) << 2;
  int s = src[i], d = dst[i];
  float4 v = *(const float4*)(node + (size_t)s * 128 + c);
  float* p = lift + (size_t)d * 128 + c;
  atomAddF(p + 0, v.x); atomAddF(p + 1, v.y);
  atomAddF(p + 2, v.z); atomAddF(p + 3, v.w);
}

// ---- scatter 2: lvl[src[i]] += relu(Y1[dst[i]]*s + t) ----------------------
__global__ __launch_bounds__(256) void k_scatter2(
    const float* __restrict__ Y1, const float* __restrict__ st,
    const int* __restrict__ src, const int* __restrict__ dst,
    float* __restrict__ lvl, int M) {
  int t = blockIdx.x * blockDim.x + threadIdx.x;
  int i = t >> 5;
  if (i >= M) return;
  int c = (t & 31) << 2;
  int s = src[i], d = dst[i];
  float4 y = *(const float4*)(Y1 + (size_t)d * 128 + c);
  float4 sc = *(const float4*)(st + c);
  float4 tc = *(const float4*)(st + 128 + c);
  float4 v;
  v.x = fmaxf(fmaf(y.x, sc.x, tc.x), 0.f);
  v.y = fmaxf(fmaf(y.y, sc.y, tc.y), 0.f);
  v.z = fmaxf(fmaf(y.z, sc.z, tc.z), 0.f);
  v.w = fmaxf(fmaf(y.w, sc.w, tc.w), 0.f);
  float* p = lvl + (size_t)s * 128 + c;
  atomAddF(p + 0, v.x); atomAddF(p + 1, v.y);
  atomAddF(p + 2, v.z); atomAddF(p + 3, v.w);
}

// ---- column stats: out[0:C]=sum, out[C:2C]=sumsq over rows -----------------
__global__ __launch_bounds__(256) void k_colstats(
    const float* __restrict__ Y, int R, int C, float* __restrict__ out) {
  __shared__ float red[512];
  int tid = threadIdx.x;
  int col = tid % C;
  int sub = tid / C;
  int tpc = 256 / C;  // 2 for C=128, 1 for C=256
  float s = 0.f, q = 0.f;
  for (long r = (long)blockIdx.x * tpc + sub; r < R; r += (long)gridDim.x * tpc) {
    float v = Y[(size_t)r * C + col];
    s += v;
    q += v * v;
  }
  if (tpc > 1) {
    red[tid] = s;
    red[256 + tid] = q;
    __syncthreads();
    if (sub == 0) {
      s += red[tid + C];
      q += red[256 + tid + C];
    }
  }
  if (sub == 0) {
    atomAddF(out + col, s);
    atomAddF(out + C + col, q);
  }
}

// ---- finalize: st[0:C]=scale, st[C:2C]=shift -------------------------------
__global__ void k_bnfin(const float* __restrict__ sums, int C, int R,
                        const float* __restrict__ g, const float* __restrict__ b,
                        float* __restrict__ st) {
  int c = blockIdx.x * blockDim.x + threadIdx.x;
  if (c >= C) return;
  float invR = 1.f / (float)R;
  float mean = sums[c] * invR;
  float var = fmaxf(sums[C + c] * invR - mean * mean, 0.f);
  float s = g[c] * rsqrtf(var + 1e-5f);
  st[c] = s;
  st[C + c] = fmaf(-mean, s, b[c]);
}

// ---- elementwise BN+ReLU -> out --------------------------------------------
__global__ __launch_bounds__(256) void k_bnrelu_out(
    const float* __restrict__ Y, const float* __restrict__ st, long R, int C,
    float* __restrict__ out) {
  long t = (long)blockIdx.x * blockDim.x + threadIdx.x;
  long idx = t * 4;
  if (idx >= R * (long)C) return;
  int c = (int)(idx % C);
  float4 y = *(const float4*)(Y + idx);
  float4 s4 = *(const float4*)(st + c);
  float4 t4 = *(const float4*)(st + C + c);
  float4 o;
  o.x = fmaxf(fmaf(y.x, s4.x, t4.x), 0.f);
  o.y = fmaxf(fmaf(y.y, s4.y, t4.y), 0.f);
  o.z = fmaxf(fmaf(y.z, s4.z, t4.z), 0.f);
  o.w = fmaxf(fmaf(y.w, s4.w, t4.w), 0.f);
  *(float4*)(out + idx) = o;
}

// ---- tiled fp32 GEMM, 64 rows x 128 cols per block, BK=16 ------------------
// MODE 1: X = concat(in0, in1) along K (each stride 128), K=256
// MODE 2: X = (1+*epsp)*in0 + in1, stride 128, K=128
// MODE 3: X = relu(in0*st[k] + st[K+k]), stride K, K=256
template <int MODE, int K>
__global__ __launch_bounds__(256) void k_gemm(
    const float* __restrict__ in0, const float* __restrict__ in1,
    const float* __restrict__ stin, const float* __restrict__ epsp,
    const float* __restrict__ W, float* __restrict__ Y, int R, int NC) {
  __shared__ float Xs[16 * 68];   // [k][row], padded stride 68
  __shared__ float Ws[16 * 132];  // [k][col], padded stride 132
  const int tid = threadIdx.x;
  const int tx = tid & 15;   // col group (8 cols: tx*4 and tx*4+64)
  const int ty = tid >> 4;   // row group (4 rows)
  const int row0 = blockIdx.x * 64;
  const int n0 = blockIdx.y * 128;
  float alpha = 0.f;
  if (MODE == 2) alpha = 1.0f + epsp[0];
  float acc[4][8];
#pragma unroll
  for (int i = 0; i < 4; ++i)
#pragma unroll
    for (int j = 0; j < 8; ++j) acc[i][j] = 0.f;

  const int r_l = tid >> 2;        // 0..63 staging row
  const int k_l = (tid & 3) << 2;  // 0,4,8,12 staging k
  const int wk = tid >> 4;         // 0..15 W staging k
  const int wn = (tid & 15) << 3;  // 0..120 W staging col
  int gr = row0 + r_l;
  if (gr >= R) gr = R - 1;  // clamp: loaded garbage rows never stored

  for (int k0 = 0; k0 < K; k0 += 16) {
    float4 x;
    if (MODE == 1) {
      const float* sp = (k0 < 128) ? in0 : in1;
      const int kk = (k0 < 128) ? (k0 + k_l) : (k0 + k_l - 128);
      x = *(const float4*)(sp + (size_t)gr * 128 + kk);
    } else if (MODE == 2) {
      const float4 a4 = *(const float4*)(in0 + (size_t)gr * 128 + k0 + k_l);
      const float4 b4 = *(const float4*)(in1 + (size_t)gr * 128 + k0 + k_l);
      x.x = fmaf(alpha, a4.x, b4.x);
      x.y = fmaf(alpha, a4.y, b4.y);
      x.z = fmaf(alpha, a4.z, b4.z);
      x.w = fmaf(alpha, a4.w, b4.w);
    } else {
      const float4 z = *(const float4*)(in0 + (size_t)gr * K + k0 + k_l);
      const float4 s4 = *(const float4*)(stin + k0 + k_l);
      const float4 t4 = *(const float4*)(stin + K + k0 + k_l);
      x.x = fmaxf(fmaf(z.x, s4.x, t4.x), 0.f);
      x.y = fmaxf(fmaf(z.y, s4.y, t4.y), 0.f);
      x.z = fmaxf(fmaf(z.z, s4.z, t4.z), 0.f);
      x.w = fmaxf(fmaf(z.w, s4.w, t4.w), 0.f);
    }
    Xs[(k_l + 0) * 68 + r_l] = x.x;
    Xs[(k_l + 1) * 68 + r_l] = x.y;
    Xs[(k_l + 2) * 68 + r_l] = x.z;
    Xs[(k_l + 3) * 68 + r_l] = x.w;
    const size_t wbase = (size_t)(k0 + wk) * NC + n0 + wn;
    const float4 w0 = *(const float4*)(W + wbase);
    const float4 w1 = *(const float4*)(W + wbase + 4);
    *(float4*)&Ws[wk * 132 + wn] = w0;
    *(float4*)&Ws[wk * 132 + wn + 4] = w1;
    __syncthreads();
#pragma unroll
    for (int kk = 0; kk < 16; ++kk) {
      const float4 a = *(const float4*)&Xs[kk * 68 + (ty << 2)];
      const float4 b0 = *(const float4*)&Ws[kk * 132 + (tx << 2)];
      const float4 b1 = *(const float4*)&Ws[kk * 132 + 64 + (tx << 2)];
      const float av[4] = {a.x, a.y, a.z, a.w};
      const float bv[8] = {b0.x, b0.y, b0.z, b0.w, b1.x, b1.y, b1.z, b1.w};
#pragma unroll
      for (int i = 0; i < 4; ++i)
#pragma unroll
        for (int j = 0; j < 8; ++j) acc[i][j] = fmaf(av[i], bv[j], acc[i][j]);
    }
    __syncthreads();
  }
  const int rbase = row0 + (ty << 2);
#pragma unroll
  for (int i = 0; i < 4; ++i) {
    const int r = rbase + i;
    if (r < R) {
      float4 o0 = make_float4(acc[i][0], acc[i][1], acc[i][2], acc[i][3]);
      float4 o1 = make_float4(acc[i][4], acc[i][5], acc[i][6], acc[i][7]);
      *(float4*)(Y + (size_t)r * NC + n0 + (tx << 2)) = o0;
      *(float4*)(Y + (size_t)r * NC + n0 + 64 + (tx << 2)) = o1;
    }
  }
}

extern "C" void kernel_launch(void* const* d_in, const int* in_sizes, int n_in,
                              void* d_out, int out_size, void* d_ws,
                              size_t ws_size, hipStream_t stream) {
  const float* node_rep = (const float*)d_in[0];
  const float* edge_rep = (const float*)d_in[1];
  const int* n2e = (const int*)d_in[2];
  const float* Wa = (const float*)d_in[3];
  const float* ga = (const float*)d_in[4];
  const float* ba = (const float*)d_in[5];
  const float* Wb1 = (const float*)d_in[6];
  const float* gb1 = (const float*)d_in[7];
  const float* bb1 = (const float*)d_in[8];
  const float* Wb2 = (const float*)d_in[9];
  const float* gb2 = (const float*)d_in[10];
  const float* bb2 = (const float*)d_in[11];
  const float* Wl1 = (const float*)d_in[12];
  const float* gl1 = (const float*)d_in[13];
  const float* bl1 = (const float*)d_in[14];
  const float* Wl2 = (const float*)d_in[15];
  const float* gl2 = (const float*)d_in[16];
  const float* bl2 = (const float*)d_in[17];
  const float* eps1 = (const float*)d_in[18];
  const float* eps2 = (const float*)d_in[19];

  const int N = in_sizes[0] / 128;
  const int E = in_sizes[1] / 128;
  const int M = in_sizes[2] / 2;
  const int* srcI = n2e;      // node index per incidence
  const int* dstI = n2e + M;  // edge index per incidence

  // ---- workspace layout (floats) ----
  float* ws = (float*)d_ws;
  size_t off = 0;
  float* lift = ws + off; off += (size_t)E * 128;   // 51.2M
  float* lvl  = ws + off; off += (size_t)N * 128;   // 6.4M
  float* buf1 = ws + off; off += (size_t)E * 128;   // 51.2M multi-use
  float* Ze   = ws + off; off += (size_t)E * 256;   // 102.4M
  float* stats = ws + off; off += 8192;
  // peak = 211.2M floats ~= 845 MB

  float* sum_a  = stats + 0;    // 256
  float* st_a   = stats + 256;  // 256
  float* sum_b1 = stats + 512;  // 512
  float* st_b1  = stats + 1024; // 512
  float* sum_b2 = stats + 1536; // 256
  float* st_b2  = stats + 1792; // 256
  float* sum_l1 = stats + 2048; // 512
  float* st_l1  = stats + 2560; // 512
  float* sum_l2 = stats + 3072; // 256
  float* st_l2  = stats + 3328; // 256

  float* Y1 = buf1;                          // [E,128]
  float* Zn = buf1;                          // [N,256] (Y1 dead by then)
  float* Y2n = buf1 + (size_t)N * 256;       // [N,128]
  float* Y2e = buf1;                         // [E,128] (node path dead)
  float* node_out = (float*)d_out;
  float* edge_out = (float*)d_out + (size_t)N * 128;

  // ---- zero accumulators (ws is poisoned 0xAA each call) ----
  hipMemsetAsync(lift, 0, (size_t)E * 128 * sizeof(float), stream);
  hipMemsetAsync(lvl, 0, (size_t)N * 128 * sizeof(float), stream);
  hipMemsetAsync(stats, 0, 8192 * sizeof(float), stream);

  const int scatterBlocks = (M * 32 + 255) / 256;

  // 1) lift_aggr = segment_sum(node_rep[src], dst, E)
  k_scatter1<<<scatterBlocks, 256, 0, stream>>>(node_rep, srcI, dstI, lift, M);

  // 2) Y1 = concat(lift, edge_rep) @ Wa ; stats ; finalize
  k_gemm<1, 256><<<dim3((E + 63) / 64, 1), 256, 0, stream>>>(
      lift, edge_rep, nullptr, nullptr, Wa, Y1, E, 128);
  k_colstats<<<512, 256, 0, stream>>>(Y1, E, 128, sum_a);
  k_bnfin<<<1, 256, 0, stream>>>(sum_a, 128, E, ga, ba, st_a);

  // 3) lvl_aggr = segment_sum(relu(Y1*s+t)[dst], src, N)
  k_scatter2<<<scatterBlocks, 256, 0, stream>>>(Y1, st_a, srcI, dstI, lvl, M);

  // 4) node path: hn = (1+eps1)*node_rep + lvl ; MLP-b
  k_gemm<2, 128><<<dim3((N + 63) / 64, 2), 256, 0, stream>>>(
      node_rep, lvl, nullptr, eps1, Wb1, Zn, N, 256);
  k_colstats<<<512, 256, 0, stream>>>(Zn, N, 256, sum_b1);
  k_bnfin<<<1, 256, 0, stream>>>(sum_b1, 256, N, gb1, bb1, st_b1);
  k_gemm<3, 256><<<dim3((N + 63) / 64, 1), 256, 0, stream>>>(
      Zn, nullptr, st_b1, nullptr, Wb2, Y2n, N, 128);
  k_colstats<<<512, 256, 0, stream>>>(Y2n, N, 128, sum_b2);
  k_bnfin<<<1, 256, 0, stream>>>(sum_b2, 128, N, gb2, bb2, st_b2);
  {
    long total = (long)N * 128 / 4;
    k_bnrelu_out<<<(int)((total + 255) / 256), 256, 0, stream>>>(
        Y2n, st_b2, N, 128, node_out);
  }

  // 5) edge path: he = (1+eps2)*edge_rep + lift ; MLP-l
  k_gemm<2, 128><<<dim3((E + 63) / 64, 2), 256, 0, stream>>>(
      edge_rep, lift, nullptr, eps2, Wl1, Ze, E, 256);
  k_colstats<<<512, 256, 0, stream>>>(Ze, E, 256, sum_l1);
  k_bnfin<<<1, 256, 0, stream>>>(sum_l1, 256, E, gl1, bl1, st_l1);
  k_gemm<3, 256><<<dim3((E + 63) / 64, 1), 256, 0, stream>>>(
      Ze, nullptr, st_l1, nullptr, Wl2, Y2e, E, 128);
  k_colstats<<<512, 256, 0, stream>>>(Y2e, E, 128, sum_l2);
  k_bnfin<<<1, 256, 0, stream>>>(sum_l2, 128, E, gl2, bl2, st_l2);
  {
    long total = (long)E * 128 / 4;
    k_bnrelu_out<<<(int)((total + 255) / 256), 256, 0, stream>>>(
        Y2e, st_l2, E, 128, edge_out);
  }
}

// Round 2
// 2596.334 us; speedup vs baseline: 1.8705x; 1.8705x over previous
//
#include <hip/hip_runtime.h>
#include <cstdint>
#include <cstddef>

// ---------------------------------------------------------------------------
// SplitLayer. Round 2: replace atomic scatters (2x1350us, cache-thrash bound)
// with CSR-based gathers. CSR built on-device per call (histogram + scan +
// fill, ~100us). GEMMs still fp32 vector-ALU (next target).
// ---------------------------------------------------------------------------

__device__ __forceinline__ void atomAddF(float* p, float v) {
  unsafeAtomicAdd(p, v);
}

// ============================ CSR construction ==============================

__global__ __launch_bounds__(256) void k_hist(
    const int* __restrict__ src, const int* __restrict__ dst, int M,
    int* __restrict__ cnt_e, int* __restrict__ cnt_n) {
  int i = blockIdx.x * blockDim.x + threadIdx.x;
  if (i >= M) return;
  atomicAdd(cnt_e + dst[i], 1);
  atomicAdd(cnt_n + src[i], 1);
}

// block-level exclusive scan: out = excl scan of in within 1024-elem block,
// bsum[b] = block total
__global__ __launch_bounds__(256) void k_scan_block(
    const int* __restrict__ in, int* __restrict__ out, int* __restrict__ bsum,
    int L) {
  __shared__ int sh[256];
  int t = threadIdx.x;
  int base = (blockIdx.x * 256 + t) * 4;
  int v[4];
#pragma unroll
  for (int j = 0; j < 4; ++j) v[j] = (base + j < L) ? in[base + j] : 0;
  int tsum = v[0] + v[1] + v[2] + v[3];
  sh[t] = tsum;
  __syncthreads();
#pragma unroll
  for (int off = 1; off < 256; off <<= 1) {
    int x = (t >= off) ? sh[t - off] : 0;
    __syncthreads();
    sh[t] += x;
    __syncthreads();
  }
  int excl = sh[t] - tsum;
  if (t == 255) bsum[blockIdx.x] = sh[255];
  int run = excl;
#pragma unroll
  for (int j = 0; j < 4; ++j) {
    if (base + j < L) out[base + j] = run;
    run += v[j];
  }
}

// single-block exclusive scan of bsum (nb <= a few thousand)
__global__ __launch_bounds__(1024) void k_scan_top(int* __restrict__ bsum,
                                                   int nb) {
  __shared__ int sh[1024];
  __shared__ int running;
  int t = threadIdx.x;
  if (t == 0) running = 0;
  __syncthreads();
  for (int c = 0; c < nb; c += 1024) {
    int i = c + t;
    int v = (i < nb) ? bsum[i] : 0;
    sh[t] = v;
    __syncthreads();
#pragma unroll
    for (int off = 1; off < 1024; off <<= 1) {
      int x = (t >= off) ? sh[t - off] : 0;
      __syncthreads();
      sh[t] += x;
      __syncthreads();
    }
    int r = running;
    if (i < nb) bsum[i] = r + sh[t] - v;  // exclusive
    __syncthreads();
    if (t == 1023) running = r + sh[1023];
    __syncthreads();
  }
}

__global__ __launch_bounds__(256) void k_scan_add(int* __restrict__ out,
                                                  const int* __restrict__ bsum,
                                                  int L) {
  int base = (blockIdx.x * 256 + threadIdx.x) * 4;
  int add = bsum[blockIdx.x];
#pragma unroll
  for (int j = 0; j < 4; ++j)
    if (base + j < L) out[base + j] += add;
}

__global__ void k_settail(int* off_e, int E, int* off_n, int N, int M) {
  off_e[E] = M;
  off_n[N] = M;
}

__global__ __launch_bounds__(256) void k_fill(
    const int* __restrict__ src, const int* __restrict__ dst, int M,
    const int* __restrict__ off_e, int* __restrict__ fill_e,
    int* __restrict__ csr_e, const int* __restrict__ off_n,
    int* __restrict__ fill_n, int* __restrict__ csr_n) {
  int i = blockIdx.x * blockDim.x + threadIdx.x;
  if (i >= M) return;
  int s = src[i], d = dst[i];
  int pe = off_e[d] + atomicAdd(fill_e + d, 1);
  csr_e[pe] = s;
  int pn = off_n[s] + atomicAdd(fill_n + s, 1);
  csr_n[pn] = d;
}

// ============================ gathers =======================================

// lift[e] = sum over incidences of node[csr_e[j]] ; one wave per edge
__global__ __launch_bounds__(256) void k_gather1(
    const float* __restrict__ node, const int* __restrict__ off_e,
    const int* __restrict__ csr_e, float* __restrict__ lift, int E) {
  int e = blockIdx.x * 4 + (threadIdx.x >> 6);
  if (e >= E) return;
  int lane = threadIdx.x & 63;
  int b = off_e[e], en = off_e[e + 1];
  float2 acc = make_float2(0.f, 0.f);
  const float2* np = (const float2*)node;
  for (int j = b; j < en; ++j) {
    int r = csr_e[j];
    float2 v = np[(size_t)r * 64 + lane];
    acc.x += v.x;
    acc.y += v.y;
  }
  ((float2*)lift)[(size_t)e * 64 + lane] = acc;
}

// lvl[n] = sum over incidences of relu(Y1[csr_n[j]]*s + t) ; one wave per node
__global__ __launch_bounds__(256) void k_gather2(
    const float* __restrict__ Y1, const float* __restrict__ st,
    const int* __restrict__ off_n, const int* __restrict__ csr_n,
    float* __restrict__ lvl, int N) {
  int n = blockIdx.x * 4 + (threadIdx.x >> 6);
  if (n >= N) return;
  int lane = threadIdx.x & 63;
  float2 sc = ((const float2*)st)[lane];
  float2 tc = ((const float2*)(st + 128))[lane];
  int b = off_n[n], en = off_n[n + 1];
  float2 acc = make_float2(0.f, 0.f);
  const float2* yp = (const float2*)Y1;
  for (int j = b; j < en; ++j) {
    int r = csr_n[j];
    float2 y = yp[(size_t)r * 64 + lane];
    acc.x += fmaxf(fmaf(y.x, sc.x, tc.x), 0.f);
    acc.y += fmaxf(fmaf(y.y, sc.y, tc.y), 0.f);
  }
  ((float2*)lvl)[(size_t)n * 64 + lane] = acc;
}

// ============================ BN stats ======================================

__global__ __launch_bounds__(256) void k_colstats(
    const float* __restrict__ Y, int R, int C, float* __restrict__ out) {
  __shared__ float red[512];
  int tid = threadIdx.x;
  int col = tid % C;
  int sub = tid / C;
  int tpc = 256 / C;
  float s = 0.f, q = 0.f;
  for (long r = (long)blockIdx.x * tpc + sub; r < R; r += (long)gridDim.x * tpc) {
    float v = Y[(size_t)r * C + col];
    s += v;
    q += v * v;
  }
  if (tpc > 1) {
    red[tid] = s;
    red[256 + tid] = q;
    __syncthreads();
    if (sub == 0) {
      s += red[tid + C];
      q += red[256 + tid + C];
    }
  }
  if (sub == 0) {
    atomAddF(out + col, s);
    atomAddF(out + C + col, q);
  }
}

__global__ void k_bnfin(const float* __restrict__ sums, int C, int R,
                        const float* __restrict__ g, const float* __restrict__ b,
                        float* __restrict__ st) {
  int c = blockIdx.x * blockDim.x + threadIdx.x;
  if (c >= C) return;
  float invR = 1.f / (float)R;
  float mean = sums[c] * invR;
  float var = fmaxf(sums[C + c] * invR - mean * mean, 0.f);
  float s = g[c] * rsqrtf(var + 1e-5f);
  st[c] = s;
  st[C + c] = fmaf(-mean, s, b[c]);
}

__global__ __launch_bounds__(256) void k_bnrelu_out(
    const float* __restrict__ Y, const float* __restrict__ st, long R, int C,
    float* __restrict__ out) {
  long t = (long)blockIdx.x * blockDim.x + threadIdx.x;
  long idx = t * 4;
  if (idx >= R * (long)C) return;
  int c = (int)(idx % C);
  float4 y = *(const float4*)(Y + idx);
  float4 s4 = *(const float4*)(st + c);
  float4 t4 = *(const float4*)(st + C + c);
  float4 o;
  o.x = fmaxf(fmaf(y.x, s4.x, t4.x), 0.f);
  o.y = fmaxf(fmaf(y.y, s4.y, t4.y), 0.f);
  o.z = fmaxf(fmaf(y.z, s4.z, t4.z), 0.f);
  o.w = fmaxf(fmaf(y.w, s4.w, t4.w), 0.f);
  *(float4*)(out + idx) = o;
}

// ============================ GEMM (fp32) ===================================
// MODE 1: X = concat(in0, in1) along K (each stride 128), K=256
// MODE 2: X = (1+*epsp)*in0 + in1, stride 128, K=128
// MODE 3: X = relu(in0*st[k] + st[K+k]), stride K, K=256
template <int MODE, int K>
__global__ __launch_bounds__(256) void k_gemm(
    const float* __restrict__ in0, const float* __restrict__ in1,
    const float* __restrict__ stin, const float* __restrict__ epsp,
    const float* __restrict__ W, float* __restrict__ Y, int R, int NC) {
  __shared__ float Xs[16 * 68];
  __shared__ float Ws[16 * 132];
  const int tid = threadIdx.x;
  const int tx = tid & 15;
  const int ty = tid >> 4;
  const int row0 = blockIdx.x * 64;
  const int n0 = blockIdx.y * 128;
  float alpha = 0.f;
  if (MODE == 2) alpha = 1.0f + epsp[0];
  float acc[4][8];
#pragma unroll
  for (int i = 0; i < 4; ++i)
#pragma unroll
    for (int j = 0; j < 8; ++j) acc[i][j] = 0.f;

  const int r_l = tid >> 2;
  const int k_l = (tid & 3) << 2;
  const int wk = tid >> 4;
  const int wn = (tid & 15) << 3;
  int gr = row0 + r_l;
  if (gr >= R) gr = R - 1;

  for (int k0 = 0; k0 < K; k0 += 16) {
    float4 x;
    if (MODE == 1) {
      const float* sp = (k0 < 128) ? in0 : in1;
      const int kk = (k0 < 128) ? (k0 + k_l) : (k0 + k_l - 128);
      x = *(const float4*)(sp + (size_t)gr * 128 + kk);
    } else if (MODE == 2) {
      const float4 a4 = *(const float4*)(in0 + (size_t)gr * 128 + k0 + k_l);
      const float4 b4 = *(const float4*)(in1 + (size_t)gr * 128 + k0 + k_l);
      x.x = fmaf(alpha, a4.x, b4.x);
      x.y = fmaf(alpha, a4.y, b4.y);
      x.z = fmaf(alpha, a4.z, b4.z);
      x.w = fmaf(alpha, a4.w, b4.w);
    } else {
      const float4 z = *(const float4*)(in0 + (size_t)gr * K + k0 + k_l);
      const float4 s4 = *(const float4*)(stin + k0 + k_l);
      const float4 t4 = *(const float4*)(stin + K + k0 + k_l);
      x.x = fmaxf(fmaf(z.x, s4.x, t4.x), 0.f);
      x.y = fmaxf(fmaf(z.y, s4.y, t4.y), 0.f);
      x.z = fmaxf(fmaf(z.z, s4.z, t4.z), 0.f);
      x.w = fmaxf(fmaf(z.w, s4.w, t4.w), 0.f);
    }
    Xs[(k_l + 0) * 68 + r_l] = x.x;
    Xs[(k_l + 1) * 68 + r_l] = x.y;
    Xs[(k_l + 2) * 68 + r_l] = x.z;
    Xs[(k_l + 3) * 68 + r_l] = x.w;
    const size_t wbase = (size_t)(k0 + wk) * NC + n0 + wn;
    const float4 w0 = *(const float4*)(W + wbase);
    const float4 w1 = *(const float4*)(W + wbase + 4);
    *(float4*)&Ws[wk * 132 + wn] = w0;
    *(float4*)&Ws[wk * 132 + wn + 4] = w1;
    __syncthreads();
#pragma unroll
    for (int kk = 0; kk < 16; ++kk) {
      const float4 a = *(const float4*)&Xs[kk * 68 + (ty << 2)];
      const float4 b0 = *(const float4*)&Ws[kk * 132 + (tx << 2)];
      const float4 b1 = *(const float4*)&Ws[kk * 132 + 64 + (tx << 2)];
      const float av[4] = {a.x, a.y, a.z, a.w};
      const float bv[8] = {b0.x, b0.y, b0.z, b0.w, b1.x, b1.y, b1.z, b1.w};
#pragma unroll
      for (int i = 0; i < 4; ++i)
#pragma unroll
        for (int j = 0; j < 8; ++j) acc[i][j] = fmaf(av[i], bv[j], acc[i][j]);
    }
    __syncthreads();
  }
  const int rbase = row0 + (ty << 2);
#pragma unroll
  for (int i = 0; i < 4; ++i) {
    const int r = rbase + i;
    if (r < R) {
      float4 o0 = make_float4(acc[i][0], acc[i][1], acc[i][2], acc[i][3]);
      float4 o1 = make_float4(acc[i][4], acc[i][5], acc[i][6], acc[i][7]);
      *(float4*)(Y + (size_t)r * NC + n0 + (tx << 2)) = o0;
      *(float4*)(Y + (size_t)r * NC + n0 + 64 + (tx << 2)) = o1;
    }
  }
}

// ============================ launch ========================================

extern "C" void kernel_launch(void* const* d_in, const int* in_sizes, int n_in,
                              void* d_out, int out_size, void* d_ws,
                              size_t ws_size, hipStream_t stream) {
  const float* node_rep = (const float*)d_in[0];
  const float* edge_rep = (const float*)d_in[1];
  const int* n2e = (const int*)d_in[2];
  const float* Wa = (const float*)d_in[3];
  const float* ga = (const float*)d_in[4];
  const float* ba = (const float*)d_in[5];
  const float* Wb1 = (const float*)d_in[6];
  const float* gb1 = (const float*)d_in[7];
  const float* bb1 = (const float*)d_in[8];
  const float* Wb2 = (const float*)d_in[9];
  const float* gb2 = (const float*)d_in[10];
  const float* bb2 = (const float*)d_in[11];
  const float* Wl1 = (const float*)d_in[12];
  const float* gl1 = (const float*)d_in[13];
  const float* bl1 = (const float*)d_in[14];
  const float* Wl2 = (const float*)d_in[15];
  const float* gl2 = (const float*)d_in[16];
  const float* bl2 = (const float*)d_in[17];
  const float* eps1 = (const float*)d_in[18];
  const float* eps2 = (const float*)d_in[19];

  const int N = in_sizes[0] / 128;
  const int E = in_sizes[1] / 128;
  const int M = in_sizes[2] / 2;
  const int* srcI = n2e;
  const int* dstI = n2e + M;

  // ---- float workspace ----
  float* ws = (float*)d_ws;
  size_t off = 0;
  float* lift = ws + off; off += (size_t)E * 128;
  float* lvl  = ws + off; off += (size_t)N * 128;
  float* buf1 = ws + off; off += (size_t)E * 128;
  float* Ze   = ws + off; off += (size_t)E * 256;
  float* stats = ws + off; off += 8192;

  float* sum_a  = stats + 0;
  float* st_a   = stats + 256;
  float* sum_b1 = stats + 512;
  float* st_b1  = stats + 1024;
  float* sum_b2 = stats + 1536;
  float* st_b2  = stats + 1792;
  float* sum_l1 = stats + 2048;
  float* st_l1  = stats + 2560;
  float* sum_l2 = stats + 3072;
  float* st_l2  = stats + 3328;

  // ---- int CSR workspace, aliased over Ze (Ze live only from step 5) ----
  int* ib = (int*)Ze;
  size_t io = 0;
  int* cnt_e  = ib + io; io += E;
  int* off_e  = ib + io; io += E + 1;
  int* fill_e = ib + io; io += E;
  int* csr_e  = ib + io; io += M;
  int* cnt_n  = ib + io; io += N;
  int* off_n  = ib + io; io += N + 1;
  int* fill_n = ib + io; io += N;
  int* csr_n  = ib + io; io += M;
  int* bsumE  = ib + io; io += 4096;
  int* bsumN  = ib + io; io += 4096;

  float* Y1 = buf1;                     // [E,128]
  float* Zn = buf1;                     // [N,256]
  float* Y2n = buf1 + (size_t)N * 256;  // [N,128]
  float* Y2e = buf1;                    // [E,128]
  float* node_out = (float*)d_out;
  float* edge_out = (float*)d_out + (size_t)N * 128;

  hipMemsetAsync(stats, 0, 8192 * sizeof(float), stream);
  hipMemsetAsync(cnt_e, 0, (size_t)E * sizeof(int), stream);
  hipMemsetAsync(fill_e, 0, (size_t)E * sizeof(int), stream);
  hipMemsetAsync(cnt_n, 0, (size_t)N * sizeof(int), stream);
  hipMemsetAsync(fill_n, 0, (size_t)N * sizeof(int), stream);

  // ---- CSR build ----
  k_hist<<<(M + 255) / 256, 256, 0, stream>>>(srcI, dstI, M, cnt_e, cnt_n);
  const int nbE = (E + 1023) / 1024;
  const int nbN = (N + 1023) / 1024;
  k_scan_block<<<nbE, 256, 0, stream>>>(cnt_e, off_e, bsumE, E);
  k_scan_top<<<1, 1024, 0, stream>>>(bsumE, nbE);
  k_scan_add<<<nbE, 256, 0, stream>>>(off_e, bsumE, E);
  k_scan_block<<<nbN, 256, 0, stream>>>(cnt_n, off_n, bsumN, N);
  k_scan_top<<<1, 1024, 0, stream>>>(bsumN, nbN);
  k_scan_add<<<nbN, 256, 0, stream>>>(off_n, bsumN, N);
  k_settail<<<1, 1, 0, stream>>>(off_e, E, off_n, N, M);
  k_fill<<<(M + 255) / 256, 256, 0, stream>>>(srcI, dstI, M, off_e, fill_e,
                                              csr_e, off_n, fill_n, csr_n);

  // 1) lift = segment_sum(node_rep[src] by dst)
  k_gather1<<<(E + 3) / 4, 256, 0, stream>>>(node_rep, off_e, csr_e, lift, E);

  // 2) Y1 = concat(lift, edge_rep) @ Wa ; stats
  k_gemm<1, 256><<<dim3((E + 63) / 64, 1), 256, 0, stream>>>(
      lift, edge_rep, nullptr, nullptr, Wa, Y1, E, 128);
  k_colstats<<<512, 256, 0, stream>>>(Y1, E, 128, sum_a);
  k_bnfin<<<1, 256, 0, stream>>>(sum_a, 128, E, ga, ba, st_a);

  // 3) lvl = segment_sum(relu(Y1*s+t)[dst] by src)
  k_gather2<<<(N + 3) / 4, 256, 0, stream>>>(Y1, st_a, off_n, csr_n, lvl, N);

  // 4) node path
  k_gemm<2, 128><<<dim3((N + 63) / 64, 2), 256, 0, stream>>>(
      node_rep, lvl, nullptr, eps1, Wb1, Zn, N, 256);
  k_colstats<<<512, 256, 0, stream>>>(Zn, N, 256, sum_b1);
  k_bnfin<<<1, 256, 0, stream>>>(sum_b1, 256, N, gb1, bb1, st_b1);
  k_gemm<3, 256><<<dim3((N + 63) / 64, 1), 256, 0, stream>>>(
      Zn, nullptr, st_b1, nullptr, Wb2, Y2n, N, 128);
  k_colstats<<<512, 256, 0, stream>>>(Y2n, N, 128, sum_b2);
  k_bnfin<<<1, 256, 0, stream>>>(sum_b2, 128, N, gb2, bb2, st_b2);
  {
    long total = (long)N * 128 / 4;
    k_bnrelu_out<<<(int)((total + 255) / 256), 256, 0, stream>>>(
        Y2n, st_b2, N, 128, node_out);
  }

  // 5) edge path (Ze region now free of CSR use)
  k_gemm<2, 128><<<dim3((E + 63) / 64, 2), 256, 0, stream>>>(
      edge_rep, lift, nullptr, eps2, Wl1, Ze, E, 256);
  k_colstats<<<512, 256, 0, stream>>>(Ze, E, 256, sum_l1);
  k_bnfin<<<1, 256, 0, stream>>>(sum_l1, 256, E, gl1, bl1, st_l1);
  k_gemm<3, 256><<<dim3((E + 63) / 64, 1), 256, 0, stream>>>(
      Ze, nullptr, st_l1, nullptr, Wl2, Y2e, E, 128);
  k_colstats<<<512, 256, 0, stream>>>(Y2e, E, 128, sum_l2);
  k_bnfin<<<1, 256, 0, stream>>>(sum_l2, 128, E, gl2, bl2, st_l2);
  {
    long total = (long)E * 128 / 4;
    k_bnrelu_out<<<(int)((total + 255) / 256), 256, 0, stream>>>(
        Y2e, st_l2, E, 128, edge_out);
  }
}

// Round 3
// 1326.836 us; speedup vs baseline: 3.6602x; 1.9568x over previous
//
#include <hip/hip_runtime.h>
#include <cstdint>
#include <cstddef>

// ---------------------------------------------------------------------------
// SplitLayer. Round 3: bf16 MFMA GEMMs with fused BN stats + bf16
// intermediates everywhere. CSR gathers (round 2) kept, now writing bf16 and
// fusing the concat / he / hn builds.
// ---------------------------------------------------------------------------

typedef __bf16 bf16_t;
typedef __bf16 bf16x2 __attribute__((ext_vector_type(2)));
typedef __bf16 bf16x8 __attribute__((ext_vector_type(8)));
typedef float f32x4 __attribute__((ext_vector_type(4)));

__device__ __forceinline__ void atomAddF(float* p, float v) {
  unsafeAtomicAdd(p, v);
}

// ============================ CSR construction ==============================

__global__ __launch_bounds__(256) void k_hist(
    const int* __restrict__ src, const int* __restrict__ dst, int M,
    int* __restrict__ cnt_e, int* __restrict__ cnt_n) {
  int i = blockIdx.x * blockDim.x + threadIdx.x;
  if (i >= M) return;
  atomicAdd(cnt_e + dst[i], 1);
  atomicAdd(cnt_n + src[i], 1);
}

__global__ __launch_bounds__(256) void k_scan_block(
    const int* __restrict__ in, int* __restrict__ out, int* __restrict__ bsum,
    int L) {
  __shared__ int sh[256];
  int t = threadIdx.x;
  int base = (blockIdx.x * 256 + t) * 4;
  int v[4];
#pragma unroll
  for (int j = 0; j < 4; ++j) v[j] = (base + j < L) ? in[base + j] : 0;
  int tsum = v[0] + v[1] + v[2] + v[3];
  sh[t] = tsum;
  __syncthreads();
#pragma unroll
  for (int off = 1; off < 256; off <<= 1) {
    int x = (t >= off) ? sh[t - off] : 0;
    __syncthreads();
    sh[t] += x;
    __syncthreads();
  }
  int excl = sh[t] - tsum;
  if (t == 255) bsum[blockIdx.x] = sh[255];
  int run = excl;
#pragma unroll
  for (int j = 0; j < 4; ++j) {
    if (base + j < L) out[base + j] = run;
    run += v[j];
  }
}

__global__ __launch_bounds__(1024) void k_scan_top(int* __restrict__ bsum,
                                                   int nb) {
  __shared__ int sh[1024];
  __shared__ int running;
  int t = threadIdx.x;
  if (t == 0) running = 0;
  __syncthreads();
  for (int c = 0; c < nb; c += 1024) {
    int i = c + t;
    int v = (i < nb) ? bsum[i] : 0;
    sh[t] = v;
    __syncthreads();
#pragma unroll
    for (int off = 1; off < 1024; off <<= 1) {
      int x = (t >= off) ? sh[t - off] : 0;
      __syncthreads();
      sh[t] += x;
      __syncthreads();
    }
    int r = running;
    if (i < nb) bsum[i] = r + sh[t] - v;
    __syncthreads();
    if (t == 1023) running = r + sh[1023];
    __syncthreads();
  }
}

__global__ __launch_bounds__(256) void k_scan_add(int* __restrict__ out,
                                                  const int* __restrict__ bsum,
                                                  int L) {
  int base = (blockIdx.x * 256 + threadIdx.x) * 4;
  int add = bsum[blockIdx.x];
#pragma unroll
  for (int j = 0; j < 4; ++j)
    if (base + j < L) out[base + j] += add;
}

__global__ void k_settail(int* off_e, int E, int* off_n, int N, int M) {
  off_e[E] = M;
  off_n[N] = M;
}

__global__ __launch_bounds__(256) void k_fill(
    const int* __restrict__ src, const int* __restrict__ dst, int M,
    const int* __restrict__ off_e, int* __restrict__ fill_e,
    int* __restrict__ csr_e, const int* __restrict__ off_n,
    int* __restrict__ fill_n, int* __restrict__ csr_n) {
  int i = blockIdx.x * blockDim.x + threadIdx.x;
  if (i >= M) return;
  int s = src[i], d = dst[i];
  int pe = off_e[d] + atomicAdd(fill_e + d, 1);
  csr_e[pe] = s;
  int pn = off_n[s] + atomicAdd(fill_n + s, 1);
  csr_n[pn] = d;
}

// ============================ weight transpose+convert ======================
// W [K][NC] fp32 -> Wt [NC][K] bf16
__global__ __launch_bounds__(256) void k_wconv(const float* __restrict__ W,
                                               bf16_t* __restrict__ Wt, int K,
                                               int NC) {
  int idx = blockIdx.x * blockDim.x + threadIdx.x;
  if (idx >= K * NC) return;
  int k = idx / NC, n = idx % NC;
  Wt[(size_t)n * K + k] = (bf16_t)W[idx];
}

// ============================ gathers (bf16 out) ============================

// per edge e: lift = sum node[csr]; Xcat=[lift|edge] bf16; he=(1+eps2)edge+lift
__global__ __launch_bounds__(256) void k_gather1(
    const float* __restrict__ node, const float* __restrict__ edge,
    const int* __restrict__ off_e, const int* __restrict__ csr_e,
    const float* __restrict__ eps2p, bf16_t* __restrict__ Xcat,
    bf16_t* __restrict__ he, int E) {
  int e = blockIdx.x * 4 + (threadIdx.x >> 6);
  if (e >= E) return;
  int lane = threadIdx.x & 63;
  float a2 = 1.0f + eps2p[0];
  int b = off_e[e], en = off_e[e + 1];
  float2 acc = make_float2(0.f, 0.f);
  const float2* np = (const float2*)node;
  for (int j = b; j < en; ++j) {
    int r = csr_e[j];
    float2 v = np[(size_t)r * 64 + lane];
    acc.x += v.x;
    acc.y += v.y;
  }
  float2 ev = ((const float2*)edge)[(size_t)e * 64 + lane];
  bf16x2* xr = (bf16x2*)(Xcat + (size_t)e * 256);
  bf16x2 lb; lb[0] = (bf16_t)acc.x; lb[1] = (bf16_t)acc.y;
  bf16x2 eb; eb[0] = (bf16_t)ev.x; eb[1] = (bf16_t)ev.y;
  xr[lane] = lb;
  xr[lane + 64] = eb;
  bf16x2 hb;
  hb[0] = (bf16_t)fmaf(a2, ev.x, acc.x);
  hb[1] = (bf16_t)fmaf(a2, ev.y, acc.y);
  ((bf16x2*)(he + (size_t)e * 128))[lane] = hb;
}

// per node n: lvl = sum relu(Y1*s+t); hn = (1+eps1)*node + lvl (bf16)
__global__ __launch_bounds__(256) void k_gather2(
    const bf16_t* __restrict__ Y1, const float* __restrict__ st,
    const float* __restrict__ node, const int* __restrict__ off_n,
    const int* __restrict__ csr_n, const float* __restrict__ eps1p,
    bf16_t* __restrict__ hn, int N) {
  int n = blockIdx.x * 4 + (threadIdx.x >> 6);
  if (n >= N) return;
  int lane = threadIdx.x & 63;
  float a1 = 1.0f + eps1p[0];
  float2 sc = ((const float2*)st)[lane];
  float2 tc = ((const float2*)(st + 128))[lane];
  int b = off_n[n], en = off_n[n + 1];
  float2 acc = make_float2(0.f, 0.f);
  for (int j = b; j < en; ++j) {
    int r = csr_n[j];
    bf16x2 y = ((const bf16x2*)(Y1 + (size_t)r * 128))[lane];
    acc.x += fmaxf(fmaf((float)y[0], sc.x, tc.x), 0.f);
    acc.y += fmaxf(fmaf((float)y[1], sc.y, tc.y), 0.f);
  }
  float2 nv = ((const float2*)node)[(size_t)n * 64 + lane];
  bf16x2 hb;
  hb[0] = (bf16_t)fmaf(a1, nv.x, acc.x);
  hb[1] = (bf16_t)fmaf(a1, nv.y, acc.y);
  ((bf16x2*)(hn + (size_t)n * 128))[lane] = hb;
}

// ============================ BN finalize / output ==========================

__global__ void k_bnfin(const float* __restrict__ sums, int C, int R,
                        const float* __restrict__ g, const float* __restrict__ b,
                        float* __restrict__ st) {
  int c = blockIdx.x * blockDim.x + threadIdx.x;
  if (c >= C) return;
  float invR = 1.f / (float)R;
  float mean = sums[c] * invR;
  float var = fmaxf(sums[C + c] * invR - mean * mean, 0.f);
  float s = g[c] * rsqrtf(var + 1e-5f);
  st[c] = s;
  st[C + c] = fmaf(-mean, s, b[c]);
}

// read Y bf16 [R][128], apply BN+ReLU, write fp32 out
__global__ __launch_bounds__(256) void k_bnrelu_out(
    const bf16_t* __restrict__ Y, const float* __restrict__ st, long R,
    float* __restrict__ out) {
  long t = (long)blockIdx.x * blockDim.x + threadIdx.x;
  long idx = t * 8;
  if (idx >= R * 128) return;
  int c = (int)(idx & 127);
  bf16x8 y = *(const bf16x8*)(Y + idx);
  float4 s0 = *(const float4*)(st + c);
  float4 s1 = *(const float4*)(st + c + 4);
  float4 t0 = *(const float4*)(st + 128 + c);
  float4 t1 = *(const float4*)(st + 128 + c + 4);
  float4 o0, o1;
  o0.x = fmaxf(fmaf((float)y[0], s0.x, t0.x), 0.f);
  o0.y = fmaxf(fmaf((float)y[1], s0.y, t0.y), 0.f);
  o0.z = fmaxf(fmaf((float)y[2], s0.z, t0.z), 0.f);
  o0.w = fmaxf(fmaf((float)y[3], s0.w, t0.w), 0.f);
  o1.x = fmaxf(fmaf((float)y[4], s1.x, t1.x), 0.f);
  o1.y = fmaxf(fmaf((float)y[5], s1.y, t1.y), 0.f);
  o1.z = fmaxf(fmaf((float)y[6], s1.z, t1.z), 0.f);
  o1.w = fmaxf(fmaf((float)y[7], s1.w, t1.w), 0.f);
  *(float4*)(out + idx) = o0;
  *(float4*)(out + idx + 4) = o1;
}

// ============================ MFMA GEMM =====================================
// Y[R][NCtot] = A[R][K] @ Wt^T  (Wt stored [NCtot][K] bf16)
// TRANSFORM=1: A' = relu(A*st[k] + st[K+k]) applied during staging.
// Fused per-column sum/sumsq accumulated into gstats[0:NCtot], [NCtot:2NCtot].
#define LDSTR 40  // padded k-stride (elements) to cut ds_read_b128 conflicts

template <int TRANSFORM>
__global__ __launch_bounds__(256) void k_mfma_gemm(
    const bf16_t* __restrict__ A, const bf16_t* __restrict__ Wt,
    const float* __restrict__ st, float* __restrict__ gstats,
    bf16_t* __restrict__ Y, int R, int K, int NCtot) {
  __shared__ bf16_t As[128 * LDSTR];
  __shared__ bf16_t Bs[128 * LDSTR];
  const int tid = threadIdx.x;
  const int wave = tid >> 6;
  const int lane = tid & 63;
  const int quad = lane >> 4;
  const int l16 = lane & 15;
  const int wm = wave & 1;   // row half
  const int wn = wave >> 1;  // col half
  const int r0 = blockIdx.x * 128;
  const int n0 = blockIdx.y * 128;

  f32x4 acc[4][4] = {};

  const int srow = tid >> 2;      // 0..63
  const int sk = (tid & 3) * 8;   // k element offset 0/8/16/24

  for (int k0 = 0; k0 < K; k0 += 32) {
#pragma unroll
    for (int p = 0; p < 2; ++p) {
      int row = p * 64 + srow;
      int gr = r0 + row;
      if (gr >= R) gr = R - 1;  // clamp; masked at store/stats
      bf16x8 v = *(const bf16x8*)(A + (size_t)gr * K + k0 + sk);
      if (TRANSFORM) {
        bf16x8 o;
#pragma unroll
        for (int i = 0; i < 8; ++i) {
          float f = (float)v[i];
          float s = st[k0 + sk + i];
          float b = st[K + k0 + sk + i];
          o[i] = (bf16_t)fmaxf(fmaf(f, s, b), 0.f);
        }
        v = o;
      }
      *(bf16x8*)&As[row * LDSTR + sk] = v;
    }
#pragma unroll
    for (int p = 0; p < 2; ++p) {
      int row = p * 64 + srow;
      bf16x8 v = *(const bf16x8*)(Wt + (size_t)(n0 + row) * K + k0 + sk);
      *(bf16x8*)&Bs[row * LDSTR + sk] = v;
    }
    __syncthreads();
    bf16x8 af[4], bfr[4];
#pragma unroll
    for (int i = 0; i < 4; ++i)
      af[i] = *(const bf16x8*)&As[(wm * 64 + i * 16 + l16) * LDSTR + quad * 8];
#pragma unroll
    for (int j = 0; j < 4; ++j)
      bfr[j] = *(const bf16x8*)&Bs[(wn * 64 + j * 16 + l16) * LDSTR + quad * 8];
#pragma unroll
    for (int i = 0; i < 4; ++i)
#pragma unroll
      for (int j = 0; j < 4; ++j)
        acc[i][j] = __builtin_amdgcn_mfma_f32_16x16x32_bf16(af[i], bfr[j],
                                                            acc[i][j], 0, 0, 0);
    __syncthreads();
  }

  // epilogue: store bf16 + per-thread column partials
  float csum[4] = {0.f, 0.f, 0.f, 0.f};
  float csq[4] = {0.f, 0.f, 0.f, 0.f};
#pragma unroll
  for (int i = 0; i < 4; ++i) {
    int baseRow = r0 + wm * 64 + i * 16 + quad * 4;
#pragma unroll
    for (int reg = 0; reg < 4; ++reg) {
      int row = baseRow + reg;
      if (row < R) {
#pragma unroll
        for (int j = 0; j < 4; ++j) {
          float v = acc[i][j][reg];
          int col = n0 + wn * 64 + j * 16 + l16;
          Y[(size_t)row * NCtot + col] = (bf16_t)v;
          csum[j] += v;
          csq[j] += v * v;
        }
      }
    }
  }
  __syncthreads();  // done reading As/Bs; reuse as reduction scratch
  float* Ssum = (float*)As;           // [128][8]
  float* Ssq = (float*)As + 1024;     // [128][8]
  int contrib = wm * 4 + quad;
#pragma unroll
  for (int j = 0; j < 4; ++j) {
    int c = wn * 64 + j * 16 + l16;
    Ssum[c * 8 + contrib] = csum[j];
    Ssq[c * 8 + contrib] = csq[j];
  }
  __syncthreads();
  if (tid < 128) {
    float s = 0.f;
#pragma unroll
    for (int k = 0; k < 8; ++k) s += Ssum[tid * 8 + k];
    atomAddF(gstats + n0 + tid, s);
  } else {
    int c = tid - 128;
    float q = 0.f;
#pragma unroll
    for (int k = 0; k < 8; ++k) q += Ssq[c * 8 + k];
    atomAddF(gstats + NCtot + n0 + c, q);
  }
}

// ============================ launch ========================================

extern "C" void kernel_launch(void* const* d_in, const int* in_sizes, int n_in,
                              void* d_out, int out_size, void* d_ws,
                              size_t ws_size, hipStream_t stream) {
  const float* node_rep = (const float*)d_in[0];
  const float* edge_rep = (const float*)d_in[1];
  const int* n2e = (const int*)d_in[2];
  const float* Wa = (const float*)d_in[3];
  const float* ga = (const float*)d_in[4];
  const float* ba = (const float*)d_in[5];
  const float* Wb1 = (const float*)d_in[6];
  const float* gb1 = (const float*)d_in[7];
  const float* bb1 = (const float*)d_in[8];
  const float* Wb2 = (const float*)d_in[9];
  const float* gb2 = (const float*)d_in[10];
  const float* bb2 = (const float*)d_in[11];
  const float* Wl1 = (const float*)d_in[12];
  const float* gl1 = (const float*)d_in[13];
  const float* bl1 = (const float*)d_in[14];
  const float* Wl2 = (const float*)d_in[15];
  const float* gl2 = (const float*)d_in[16];
  const float* bl2 = (const float*)d_in[17];
  const float* eps1 = (const float*)d_in[18];
  const float* eps2 = (const float*)d_in[19];

  const int N = in_sizes[0] / 128;
  const int E = in_sizes[1] / 128;
  const int M = in_sizes[2] / 2;
  const int* srcI = n2e;
  const int* dstI = n2e + M;

  // ---- workspace layout ----
  char* wsb = (char*)d_ws;
  size_t off = 0;
  auto alloc = [&](size_t bytes) {
    void* p = wsb + off;
    off += (bytes + 255) & ~(size_t)255;
    return p;
  };
  bf16_t* Xcat = (bf16_t*)alloc((size_t)E * 256 * 2);
  bf16_t* he   = (bf16_t*)alloc((size_t)E * 128 * 2);
  bf16_t* Y1   = (bf16_t*)alloc((size_t)E * 128 * 2);
  bf16_t* Ze   = (bf16_t*)alloc((size_t)E * 256 * 2);
  bf16_t* Y2e  = (bf16_t*)alloc((size_t)E * 128 * 2);
  bf16_t* hn   = (bf16_t*)alloc((size_t)N * 128 * 2);
  bf16_t* Zn   = (bf16_t*)alloc((size_t)N * 256 * 2);
  bf16_t* Y2n  = (bf16_t*)alloc((size_t)N * 128 * 2);
  bf16_t* Wa_t  = (bf16_t*)alloc(256 * 128 * 2);
  bf16_t* Wb1_t = (bf16_t*)alloc(128 * 256 * 2);
  bf16_t* Wb2_t = (bf16_t*)alloc(256 * 128 * 2);
  bf16_t* Wl1_t = (bf16_t*)alloc(128 * 256 * 2);
  bf16_t* Wl2_t = (bf16_t*)alloc(256 * 128 * 2);
  int* cnt_e  = (int*)alloc((size_t)E * 4);
  int* off_e  = (int*)alloc((size_t)(E + 1) * 4);
  int* fill_e = (int*)alloc((size_t)E * 4);
  int* csr_e  = (int*)alloc((size_t)M * 4);
  int* cnt_n  = (int*)alloc((size_t)N * 4);
  int* off_n  = (int*)alloc((size_t)(N + 1) * 4);
  int* fill_n = (int*)alloc((size_t)N * 4);
  int* csr_n  = (int*)alloc((size_t)M * 4);
  int* bsumE  = (int*)alloc(4096 * 4);
  int* bsumN  = (int*)alloc(4096 * 4);
  float* stats = (float*)alloc(8192 * 4);

  float* sum_a  = stats + 0;     // 256 (sum|sq)
  float* st_a   = stats + 256;   // 256 (scale|shift)
  float* sum_b1 = stats + 512;   // 512
  float* st_b1  = stats + 1024;  // 512
  float* sum_b2 = stats + 1536;  // 256
  float* st_b2  = stats + 1792;  // 256
  float* sum_l1 = stats + 2048;  // 512
  float* st_l1  = stats + 2560;  // 512
  float* sum_l2 = stats + 3072;  // 256
  float* st_l2  = stats + 3328;  // 256

  float* node_out = (float*)d_out;
  float* edge_out = (float*)d_out + (size_t)N * 128;

  hipMemsetAsync(stats, 0, 8192 * sizeof(float), stream);
  hipMemsetAsync(cnt_e, 0, (size_t)E * sizeof(int), stream);
  hipMemsetAsync(fill_e, 0, (size_t)E * sizeof(int), stream);
  hipMemsetAsync(cnt_n, 0, (size_t)N * sizeof(int), stream);
  hipMemsetAsync(fill_n, 0, (size_t)N * sizeof(int), stream);

  // ---- CSR build ----
  k_hist<<<(M + 255) / 256, 256, 0, stream>>>(srcI, dstI, M, cnt_e, cnt_n);
  const int nbE = (E + 1023) / 1024;
  const int nbN = (N + 1023) / 1024;
  k_scan_block<<<nbE, 256, 0, stream>>>(cnt_e, off_e, bsumE, E);
  k_scan_top<<<1, 1024, 0, stream>>>(bsumE, nbE);
  k_scan_add<<<nbE, 256, 0, stream>>>(off_e, bsumE, E);
  k_scan_block<<<nbN, 256, 0, stream>>>(cnt_n, off_n, bsumN, N);
  k_scan_top<<<1, 1024, 0, stream>>>(bsumN, nbN);
  k_scan_add<<<nbN, 256, 0, stream>>>(off_n, bsumN, N);
  k_settail<<<1, 1, 0, stream>>>(off_e, E, off_n, N, M);
  k_fill<<<(M + 255) / 256, 256, 0, stream>>>(srcI, dstI, M, off_e, fill_e,
                                              csr_e, off_n, fill_n, csr_n);

  // ---- weight conversion ----
  k_wconv<<<128, 256, 0, stream>>>(Wa, Wa_t, 256, 128);
  k_wconv<<<128, 256, 0, stream>>>(Wb1, Wb1_t, 128, 256);
  k_wconv<<<128, 256, 0, stream>>>(Wb2, Wb2_t, 256, 128);
  k_wconv<<<128, 256, 0, stream>>>(Wl1, Wl1_t, 128, 256);
  k_wconv<<<128, 256, 0, stream>>>(Wl2, Wl2_t, 256, 128);

  // 1) gather1: lift/Xcat/he
  k_gather1<<<(E + 3) / 4, 256, 0, stream>>>(node_rep, edge_rep, off_e, csr_e,
                                             eps2, Xcat, he, E);

  // 2) Y1 = Xcat @ Wa (+stats)
  k_mfma_gemm<0><<<dim3((E + 127) / 128, 1), 256, 0, stream>>>(
      Xcat, Wa_t, nullptr, sum_a, Y1, E, 256, 128);
  k_bnfin<<<1, 256, 0, stream>>>(sum_a, 128, E, ga, ba, st_a);

  // 3) gather2: lvl + hn
  k_gather2<<<(N + 3) / 4, 256, 0, stream>>>(Y1, st_a, node_rep, off_n, csr_n,
                                             eps1, hn, N);

  // 4) node path
  k_mfma_gemm<0><<<dim3((N + 127) / 128, 2), 256, 0, stream>>>(
      hn, Wb1_t, nullptr, sum_b1, Zn, N, 128, 256);
  k_bnfin<<<1, 256, 0, stream>>>(sum_b1, 256, N, gb1, bb1, st_b1);
  k_mfma_gemm<1><<<dim3((N + 127) / 128, 1), 256, 0, stream>>>(
      Zn, Wb2_t, st_b1, sum_b2, Y2n, N, 256, 128);
  k_bnfin<<<1, 256, 0, stream>>>(sum_b2, 128, N, gb2, bb2, st_b2);
  {
    long total = ((long)N * 128 + 7) / 8;
    k_bnrelu_out<<<(int)((total + 255) / 256), 256, 0, stream>>>(Y2n, st_b2, N,
                                                                 node_out);
  }

  // 5) edge path
  k_mfma_gemm<0><<<dim3((E + 127) / 128, 2), 256, 0, stream>>>(
      he, Wl1_t, nullptr, sum_l1, Ze, E, 128, 256);
  k_bnfin<<<1, 256, 0, stream>>>(sum_l1, 256, E, gl1, bl1, st_l1);
  k_mfma_gemm<1><<<dim3((E + 127) / 128, 1), 256, 0, stream>>>(
      Ze, Wl2_t, st_l1, sum_l2, Y2e, E, 256, 128);
  k_bnfin<<<1, 256, 0, stream>>>(sum_l2, 128, E, gl2, bl2, st_l2);
  {
    long total = ((long)E * 128 + 7) / 8;
    k_bnrelu_out<<<(int)((total + 255) / 256), 256, 0, stream>>>(Y2e, st_l2, E,
                                                                 edge_out);
  }
}

// Round 4
// 1201.680 us; speedup vs baseline: 4.0414x; 1.1042x over previous
//
#include <hip/hip_runtime.h>
#include <cstdint>
#include <cstddef>

// ---------------------------------------------------------------------------
// SplitLayer. Round 4: gather1 reduced to pure lift-gather (ILP'd); GEMM-1
// fuses the [lift|edge] concat staging and emits he=(1+eps2)edge+lift as a
// side product. gather2 gets 4 load chains/wave. Single merged memset.
// ---------------------------------------------------------------------------

typedef __bf16 bf16_t;
typedef __bf16 bf16x2 __attribute__((ext_vector_type(2)));
typedef __bf16 bf16x4 __attribute__((ext_vector_type(4)));
typedef __bf16 bf16x8 __attribute__((ext_vector_type(8)));
typedef float f32x4 __attribute__((ext_vector_type(4)));

__device__ __forceinline__ void atomAddF(float* p, float v) {
  unsafeAtomicAdd(p, v);
}

// ============================ CSR construction ==============================

__global__ __launch_bounds__(256) void k_hist(
    const int* __restrict__ src, const int* __restrict__ dst, int M,
    int* __restrict__ cnt_e, int* __restrict__ cnt_n) {
  int i = blockIdx.x * blockDim.x + threadIdx.x;
  if (i >= M) return;
  atomicAdd(cnt_e + dst[i], 1);
  atomicAdd(cnt_n + src[i], 1);
}

__global__ __launch_bounds__(256) void k_scan_block(
    const int* __restrict__ in, int* __restrict__ out, int* __restrict__ bsum,
    int L) {
  __shared__ int sh[256];
  int t = threadIdx.x;
  int base = (blockIdx.x * 256 + t) * 4;
  int v[4];
#pragma unroll
  for (int j = 0; j < 4; ++j) v[j] = (base + j < L) ? in[base + j] : 0;
  int tsum = v[0] + v[1] + v[2] + v[3];
  sh[t] = tsum;
  __syncthreads();
#pragma unroll
  for (int off = 1; off < 256; off <<= 1) {
    int x = (t >= off) ? sh[t - off] : 0;
    __syncthreads();
    sh[t] += x;
    __syncthreads();
  }
  int excl = sh[t] - tsum;
  if (t == 255) bsum[blockIdx.x] = sh[255];
  int run = excl;
#pragma unroll
  for (int j = 0; j < 4; ++j) {
    if (base + j < L) out[base + j] = run;
    run += v[j];
  }
}

__global__ __launch_bounds__(1024) void k_scan_top(int* __restrict__ bsum,
                                                   int nb) {
  __shared__ int sh[1024];
  __shared__ int running;
  int t = threadIdx.x;
  if (t == 0) running = 0;
  __syncthreads();
  for (int c = 0; c < nb; c += 1024) {
    int i = c + t;
    int v = (i < nb) ? bsum[i] : 0;
    sh[t] = v;
    __syncthreads();
#pragma unroll
    for (int off = 1; off < 1024; off <<= 1) {
      int x = (t >= off) ? sh[t - off] : 0;
      __syncthreads();
      sh[t] += x;
      __syncthreads();
    }
    int r = running;
    if (i < nb) bsum[i] = r + sh[t] - v;
    __syncthreads();
    if (t == 1023) running = r + sh[1023];
    __syncthreads();
  }
}

__global__ __launch_bounds__(256) void k_scan_add(int* __restrict__ out,
                                                  const int* __restrict__ bsum,
                                                  int L) {
  int base = (blockIdx.x * 256 + threadIdx.x) * 4;
  int add = bsum[blockIdx.x];
#pragma unroll
  for (int j = 0; j < 4; ++j)
    if (base + j < L) out[base + j] += add;
}

__global__ void k_settail(int* off_e, int E, int* off_n, int N, int M) {
  off_e[E] = M;
  off_n[N] = M;
}

__global__ __launch_bounds__(256) void k_fill(
    const int* __restrict__ src, const int* __restrict__ dst, int M,
    const int* __restrict__ off_e, int* __restrict__ fill_e,
    int* __restrict__ csr_e, const int* __restrict__ off_n,
    int* __restrict__ fill_n, int* __restrict__ csr_n) {
  int i = blockIdx.x * blockDim.x + threadIdx.x;
  if (i >= M) return;
  int s = src[i], d = dst[i];
  int pe = off_e[d] + atomicAdd(fill_e + d, 1);
  csr_e[pe] = s;
  int pn = off_n[s] + atomicAdd(fill_n + s, 1);
  csr_n[pn] = d;
}

// ============================ weight transpose+convert ======================
__global__ __launch_bounds__(256) void k_wconv(const float* __restrict__ W,
                                               bf16_t* __restrict__ Wt, int K,
                                               int NC) {
  int idx = blockIdx.x * blockDim.x + threadIdx.x;
  if (idx >= K * NC) return;
  int k = idx / NC, n = idx % NC;
  Wt[(size_t)n * K + k] = (bf16_t)W[idx];
}

// ============================ gather1: lift only ============================
// 2 edges per wave, 32 lanes per edge (float4/lane). lift bf16 out.
__global__ __launch_bounds__(256) void k_gather1(
    const float* __restrict__ node, const int* __restrict__ off_e,
    const int* __restrict__ csr_e, bf16_t* __restrict__ lift, int E) {
  int e = blockIdx.x * 8 + (threadIdx.x >> 5);
  if (e >= E) return;
  int l = threadIdx.x & 31;
  int b = off_e[e], en = off_e[e + 1];
  float4 acc = make_float4(0.f, 0.f, 0.f, 0.f);
  for (int j = b; j < en; ++j) {
    int r = csr_e[j];
    float4 v = *(const float4*)(node + (size_t)r * 128 + l * 4);
    acc.x += v.x; acc.y += v.y; acc.z += v.z; acc.w += v.w;
  }
  bf16x4 o;
  o[0] = (bf16_t)acc.x; o[1] = (bf16_t)acc.y;
  o[2] = (bf16_t)acc.z; o[3] = (bf16_t)acc.w;
  *(bf16x4*)(lift + (size_t)e * 128 + l * 4) = o;
}

// ============================ gather2: lvl + hn =============================
// 4 nodes per wave, 16 lanes per node (bf16x8/lane): 4 concurrent chains.
__global__ __launch_bounds__(256) void k_gather2(
    const bf16_t* __restrict__ Y1, const float* __restrict__ st,
    const float* __restrict__ node, const int* __restrict__ off_n,
    const int* __restrict__ csr_n, const float* __restrict__ eps1p,
    bf16_t* __restrict__ hn, int N) {
  int n = blockIdx.x * 16 + (threadIdx.x >> 4);
  if (n >= N) return;
  int l = threadIdx.x & 15;
  float a1 = 1.0f + eps1p[0];
  float4 s0 = *(const float4*)(st + l * 8);
  float4 s1 = *(const float4*)(st + l * 8 + 4);
  float4 t0 = *(const float4*)(st + 128 + l * 8);
  float4 t1 = *(const float4*)(st + 128 + l * 8 + 4);
  float acc[8] = {0.f, 0.f, 0.f, 0.f, 0.f, 0.f, 0.f, 0.f};
  int b = off_n[n], en = off_n[n + 1];
  for (int j = b; j < en; ++j) {
    int r = csr_n[j];
    bf16x8 y = *(const bf16x8*)(Y1 + (size_t)r * 128 + l * 8);
    acc[0] += fmaxf(fmaf((float)y[0], s0.x, t0.x), 0.f);
    acc[1] += fmaxf(fmaf((float)y[1], s0.y, t0.y), 0.f);
    acc[2] += fmaxf(fmaf((float)y[2], s0.z, t0.z), 0.f);
    acc[3] += fmaxf(fmaf((float)y[3], s0.w, t0.w), 0.f);
    acc[4] += fmaxf(fmaf((float)y[4], s1.x, t1.x), 0.f);
    acc[5] += fmaxf(fmaf((float)y[5], s1.y, t1.y), 0.f);
    acc[6] += fmaxf(fmaf((float)y[6], s1.z, t1.z), 0.f);
    acc[7] += fmaxf(fmaf((float)y[7], s1.w, t1.w), 0.f);
  }
  float4 n0 = *(const float4*)(node + (size_t)n * 128 + l * 8);
  float4 n1 = *(const float4*)(node + (size_t)n * 128 + l * 8 + 4);
  bf16x8 hb;
  hb[0] = (bf16_t)fmaf(a1, n0.x, acc[0]);
  hb[1] = (bf16_t)fmaf(a1, n0.y, acc[1]);
  hb[2] = (bf16_t)fmaf(a1, n0.z, acc[2]);
  hb[3] = (bf16_t)fmaf(a1, n0.w, acc[3]);
  hb[4] = (bf16_t)fmaf(a1, n1.x, acc[4]);
  hb[5] = (bf16_t)fmaf(a1, n1.y, acc[5]);
  hb[6] = (bf16_t)fmaf(a1, n1.z, acc[6]);
  hb[7] = (bf16_t)fmaf(a1, n1.w, acc[7]);
  *(bf16x8*)(hn + (size_t)n * 128 + l * 8) = hb;
}

// ============================ BN finalize / output ==========================

__global__ void k_bnfin(const float* __restrict__ sums, int C, int R,
                        const float* __restrict__ g, const float* __restrict__ b,
                        float* __restrict__ st) {
  int c = blockIdx.x * blockDim.x + threadIdx.x;
  if (c >= C) return;
  float invR = 1.f / (float)R;
  float mean = sums[c] * invR;
  float var = fmaxf(sums[C + c] * invR - mean * mean, 0.f);
  float s = g[c] * rsqrtf(var + 1e-5f);
  st[c] = s;
  st[C + c] = fmaf(-mean, s, b[c]);
}

__global__ __launch_bounds__(256) void k_bnrelu_out(
    const bf16_t* __restrict__ Y, const float* __restrict__ st, long R,
    float* __restrict__ out) {
  long t = (long)blockIdx.x * blockDim.x + threadIdx.x;
  long idx = t * 8;
  if (idx >= R * 128) return;
  int c = (int)(idx & 127);
  bf16x8 y = *(const bf16x8*)(Y + idx);
  float4 s0 = *(const float4*)(st + c);
  float4 s1 = *(const float4*)(st + c + 4);
  float4 t0 = *(const float4*)(st + 128 + c);
  float4 t1 = *(const float4*)(st + 128 + c + 4);
  float4 o0, o1;
  o0.x = fmaxf(fmaf((float)y[0], s0.x, t0.x), 0.f);
  o0.y = fmaxf(fmaf((float)y[1], s0.y, t0.y), 0.f);
  o0.z = fmaxf(fmaf((float)y[2], s0.z, t0.z), 0.f);
  o0.w = fmaxf(fmaf((float)y[3], s0.w, t0.w), 0.f);
  o1.x = fmaxf(fmaf((float)y[4], s1.x, t1.x), 0.f);
  o1.y = fmaxf(fmaf((float)y[5], s1.y, t1.y), 0.f);
  o1.z = fmaxf(fmaf((float)y[6], s1.z, t1.z), 0.f);
  o1.w = fmaxf(fmaf((float)y[7], s1.w, t1.w), 0.f);
  *(float4*)(out + idx) = o0;
  *(float4*)(out + idx + 4) = o1;
}

// ============================ MFMA GEMM (generic) ===========================
#define LDSTR 40

template <int TRANSFORM>
__global__ __launch_bounds__(256) void k_mfma_gemm(
    const bf16_t* __restrict__ A, const bf16_t* __restrict__ Wt,
    const float* __restrict__ st, float* __restrict__ gstats,
    bf16_t* __restrict__ Y, int R, int K, int NCtot) {
  __shared__ bf16_t As[128 * LDSTR];
  __shared__ bf16_t Bs[128 * LDSTR];
  const int tid = threadIdx.x;
  const int wave = tid >> 6;
  const int lane = tid & 63;
  const int quad = lane >> 4;
  const int l16 = lane & 15;
  const int wm = wave & 1;
  const int wn = wave >> 1;
  const int r0 = blockIdx.x * 128;
  const int n0 = blockIdx.y * 128;

  f32x4 acc[4][4] = {};
  const int srow = tid >> 2;
  const int sk = (tid & 3) * 8;

  for (int k0 = 0; k0 < K; k0 += 32) {
#pragma unroll
    for (int p = 0; p < 2; ++p) {
      int row = p * 64 + srow;
      int gr = r0 + row;
      if (gr >= R) gr = R - 1;
      bf16x8 v = *(const bf16x8*)(A + (size_t)gr * K + k0 + sk);
      if (TRANSFORM) {
        bf16x8 o;
#pragma unroll
        for (int i = 0; i < 8; ++i) {
          float f = (float)v[i];
          float s = st[k0 + sk + i];
          float b = st[K + k0 + sk + i];
          o[i] = (bf16_t)fmaxf(fmaf(f, s, b), 0.f);
        }
        v = o;
      }
      *(bf16x8*)&As[row * LDSTR + sk] = v;
    }
#pragma unroll
    for (int p = 0; p < 2; ++p) {
      int row = p * 64 + srow;
      bf16x8 v = *(const bf16x8*)(Wt + (size_t)(n0 + row) * K + k0 + sk);
      *(bf16x8*)&Bs[row * LDSTR + sk] = v;
    }
    __syncthreads();
    bf16x8 af[4], bfr[4];
#pragma unroll
    for (int i = 0; i < 4; ++i)
      af[i] = *(const bf16x8*)&As[(wm * 64 + i * 16 + l16) * LDSTR + quad * 8];
#pragma unroll
    for (int j = 0; j < 4; ++j)
      bfr[j] = *(const bf16x8*)&Bs[(wn * 64 + j * 16 + l16) * LDSTR + quad * 8];
#pragma unroll
    for (int i = 0; i < 4; ++i)
#pragma unroll
      for (int j = 0; j < 4; ++j)
        acc[i][j] = __builtin_amdgcn_mfma_f32_16x16x32_bf16(af[i], bfr[j],
                                                            acc[i][j], 0, 0, 0);
    __syncthreads();
  }

  float csum[4] = {0.f, 0.f, 0.f, 0.f};
  float csq[4] = {0.f, 0.f, 0.f, 0.f};
#pragma unroll
  for (int i = 0; i < 4; ++i) {
    int baseRow = r0 + wm * 64 + i * 16 + quad * 4;
#pragma unroll
    for (int reg = 0; reg < 4; ++reg) {
      int row = baseRow + reg;
      if (row < R) {
#pragma unroll
        for (int j = 0; j < 4; ++j) {
          float v = acc[i][j][reg];
          int col = n0 + wn * 64 + j * 16 + l16;
          Y[(size_t)row * NCtot + col] = (bf16_t)v;
          csum[j] += v;
          csq[j] += v * v;
        }
      }
    }
  }
  __syncthreads();
  float* Ssum = (float*)As;
  float* Ssq = (float*)As + 1024;
  int contrib = wm * 4 + quad;
#pragma unroll
  for (int j = 0; j < 4; ++j) {
    int c = wn * 64 + j * 16 + l16;
    Ssum[c * 8 + contrib] = csum[j];
    Ssq[c * 8 + contrib] = csq[j];
  }
  __syncthreads();
  if (tid < 128) {
    float s = 0.f;
#pragma unroll
    for (int k = 0; k < 8; ++k) s += Ssum[tid * 8 + k];
    atomAddF(gstats + n0 + tid, s);
  } else {
    int c = tid - 128;
    float q = 0.f;
#pragma unroll
    for (int k = 0; k < 8; ++k) q += Ssq[c * 8 + k];
    atomAddF(gstats + NCtot + n0 + c, q);
  }
}

// ============================ MFMA GEMM cat (GEMM-1) ========================
// A = [lift | edge] (K=256, NC=128). lift bf16 [R][128]; edge fp32 [R][128].
// Emits he = lift + (1+eps2)*edge during edge-phase staging.
__global__ __launch_bounds__(256) void k_mfma_gemm_cat(
    const bf16_t* __restrict__ lift, const float* __restrict__ edge,
    const bf16_t* __restrict__ Wt, const float* __restrict__ eps2p,
    float* __restrict__ gstats, bf16_t* __restrict__ Y,
    bf16_t* __restrict__ he, int R) {
  __shared__ bf16_t As[128 * LDSTR];
  __shared__ bf16_t Bs[128 * LDSTR];
  const int tid = threadIdx.x;
  const int wave = tid >> 6;
  const int lane = tid & 63;
  const int quad = lane >> 4;
  const int l16 = lane & 15;
  const int wm = wave & 1;
  const int wn = wave >> 1;
  const int r0 = blockIdx.x * 128;
  const float a2 = 1.0f + eps2p[0];

  f32x4 acc[4][4] = {};
  const int srow = tid >> 2;
  const int sk = (tid & 3) * 8;
  bf16x8 lreg[4][2];  // lift chunks kept for he emission

  for (int ph = 0; ph < 8; ++ph) {
    const int k0 = ph * 32;
#pragma unroll
    for (int p = 0; p < 2; ++p) {
      int row = p * 64 + srow;
      int gr = r0 + row;
      if (gr >= R) gr = R - 1;
      bf16x8 v;
      if (ph < 4) {
        v = *(const bf16x8*)(lift + (size_t)gr * 128 + k0 + sk);
        lreg[ph][p] = v;
      } else {
        const int kk = k0 - 128;
        float4 e0 = *(const float4*)(edge + (size_t)gr * 128 + kk + sk);
        float4 e1 = *(const float4*)(edge + (size_t)gr * 128 + kk + sk + 4);
        const float ef[8] = {e0.x, e0.y, e0.z, e0.w, e1.x, e1.y, e1.z, e1.w};
        bf16x8 lv = lreg[ph - 4][p];
        bf16x8 hv;
#pragma unroll
        for (int i = 0; i < 8; ++i) {
          v[i] = (bf16_t)ef[i];
          hv[i] = (bf16_t)fmaf(a2, ef[i], (float)lv[i]);
        }
        *(bf16x8*)(he + (size_t)gr * 128 + kk + sk) = hv;
      }
      *(bf16x8*)&As[row * LDSTR + sk] = v;
    }
#pragma unroll
    for (int p = 0; p < 2; ++p) {
      int row = p * 64 + srow;
      bf16x8 v = *(const bf16x8*)(Wt + (size_t)row * 256 + k0 + sk);
      *(bf16x8*)&Bs[row * LDSTR + sk] = v;
    }
    __syncthreads();
    bf16x8 af[4], bfr[4];
#pragma unroll
    for (int i = 0; i < 4; ++i)
      af[i] = *(const bf16x8*)&As[(wm * 64 + i * 16 + l16) * LDSTR + quad * 8];
#pragma unroll
    for (int j = 0; j < 4; ++j)
      bfr[j] = *(const bf16x8*)&Bs[(wn * 64 + j * 16 + l16) * LDSTR + quad * 8];
#pragma unroll
    for (int i = 0; i < 4; ++i)
#pragma unroll
      for (int j = 0; j < 4; ++j)
        acc[i][j] = __builtin_amdgcn_mfma_f32_16x16x32_bf16(af[i], bfr[j],
                                                            acc[i][j], 0, 0, 0);
    __syncthreads();
  }

  float csum[4] = {0.f, 0.f, 0.f, 0.f};
  float csq[4] = {0.f, 0.f, 0.f, 0.f};
#pragma unroll
  for (int i = 0; i < 4; ++i) {
    int baseRow = r0 + wm * 64 + i * 16 + quad * 4;
#pragma unroll
    for (int reg = 0; reg < 4; ++reg) {
      int row = baseRow + reg;
      if (row < R) {
#pragma unroll
        for (int j = 0; j < 4; ++j) {
          float v = acc[i][j][reg];
          int col = wn * 64 + j * 16 + l16;
          Y[(size_t)row * 128 + col] = (bf16_t)v;
          csum[j] += v;
          csq[j] += v * v;
        }
      }
    }
  }
  __syncthreads();
  float* Ssum = (float*)As;
  float* Ssq = (float*)As + 1024;
  int contrib = wm * 4 + quad;
#pragma unroll
  for (int j = 0; j < 4; ++j) {
    int c = wn * 64 + j * 16 + l16;
    Ssum[c * 8 + contrib] = csum[j];
    Ssq[c * 8 + contrib] = csq[j];
  }
  __syncthreads();
  if (tid < 128) {
    float s = 0.f;
#pragma unroll
    for (int k = 0; k < 8; ++k) s += Ssum[tid * 8 + k];
    atomAddF(gstats + tid, s);
  } else {
    int c = tid - 128;
    float q = 0.f;
#pragma unroll
    for (int k = 0; k < 8; ++k) q += Ssq[c * 8 + k];
    atomAddF(gstats + 128 + c, q);
  }
}

// ============================ launch ========================================

extern "C" void kernel_launch(void* const* d_in, const int* in_sizes, int n_in,
                              void* d_out, int out_size, void* d_ws,
                              size_t ws_size, hipStream_t stream) {
  const float* node_rep = (const float*)d_in[0];
  const float* edge_rep = (const float*)d_in[1];
  const int* n2e = (const int*)d_in[2];
  const float* Wa = (const float*)d_in[3];
  const float* ga = (const float*)d_in[4];
  const float* ba = (const float*)d_in[5];
  const float* Wb1 = (const float*)d_in[6];
  const float* gb1 = (const float*)d_in[7];
  const float* bb1 = (const float*)d_in[8];
  const float* Wb2 = (const float*)d_in[9];
  const float* gb2 = (const float*)d_in[10];
  const float* bb2 = (const float*)d_in[11];
  const float* Wl1 = (const float*)d_in[12];
  const float* gl1 = (const float*)d_in[13];
  const float* bl1 = (const float*)d_in[14];
  const float* Wl2 = (const float*)d_in[15];
  const float* gl2 = (const float*)d_in[16];
  const float* bl2 = (const float*)d_in[17];
  const float* eps1 = (const float*)d_in[18];
  const float* eps2 = (const float*)d_in[19];

  const int N = in_sizes[0] / 128;
  const int E = in_sizes[1] / 128;
  const int M = in_sizes[2] / 2;
  const int* srcI = n2e;
  const int* dstI = n2e + M;

  char* wsb = (char*)d_ws;
  size_t off = 0;
  auto alloc = [&](size_t bytes) {
    void* p = wsb + off;
    off += (bytes + 255) & ~(size_t)255;
    return p;
  };
  bf16_t* lift = (bf16_t*)alloc((size_t)E * 128 * 2);
  bf16_t* he   = (bf16_t*)alloc((size_t)E * 128 * 2);
  bf16_t* Y1   = (bf16_t*)alloc((size_t)E * 128 * 2);
  bf16_t* Ze   = (bf16_t*)alloc((size_t)E * 256 * 2);
  bf16_t* Y2e  = (bf16_t*)alloc((size_t)E * 128 * 2);
  bf16_t* hn   = (bf16_t*)alloc((size_t)N * 128 * 2);
  bf16_t* Zn   = (bf16_t*)alloc((size_t)N * 256 * 2);
  bf16_t* Y2n  = (bf16_t*)alloc((size_t)N * 128 * 2);
  bf16_t* Wa_t  = (bf16_t*)alloc(256 * 128 * 2);
  bf16_t* Wb1_t = (bf16_t*)alloc(128 * 256 * 2);
  bf16_t* Wb2_t = (bf16_t*)alloc(256 * 128 * 2);
  bf16_t* Wl1_t = (bf16_t*)alloc(128 * 256 * 2);
  bf16_t* Wl2_t = (bf16_t*)alloc(256 * 128 * 2);
  // zero-init region: cnt_e, fill_e, cnt_n, fill_n, stats (contiguous)
  int* zbase  = (int*)alloc(((size_t)E * 2 + (size_t)N * 2 + 8192) * 4);
  int* cnt_e  = zbase;
  int* fill_e = zbase + E;
  int* cnt_n  = zbase + 2 * (size_t)E;
  int* fill_n = zbase + 2 * (size_t)E + N;
  float* stats = (float*)(zbase + 2 * (size_t)E + 2 * (size_t)N);
  int* off_e  = (int*)alloc((size_t)(E + 1) * 4);
  int* csr_e  = (int*)alloc((size_t)M * 4);
  int* off_n  = (int*)alloc((size_t)(N + 1) * 4);
  int* csr_n  = (int*)alloc((size_t)M * 4);
  int* bsumE  = (int*)alloc(4096 * 4);
  int* bsumN  = (int*)alloc(4096 * 4);

  float* sum_a  = stats + 0;
  float* st_a   = stats + 256;
  float* sum_b1 = stats + 512;
  float* st_b1  = stats + 1024;
  float* sum_b2 = stats + 1536;
  float* st_b2  = stats + 1792;
  float* sum_l1 = stats + 2048;
  float* st_l1  = stats + 2560;
  float* sum_l2 = stats + 3072;
  float* st_l2  = stats + 3328;

  float* node_out = (float*)d_out;
  float* edge_out = (float*)d_out + (size_t)N * 128;

  hipMemsetAsync(zbase, 0, ((size_t)E * 2 + (size_t)N * 2 + 8192) * 4, stream);

  // ---- CSR build ----
  k_hist<<<(M + 255) / 256, 256, 0, stream>>>(srcI, dstI, M, cnt_e, cnt_n);
  const int nbE = (E + 1023) / 1024;
  const int nbN = (N + 1023) / 1024;
  k_scan_block<<<nbE, 256, 0, stream>>>(cnt_e, off_e, bsumE, E);
  k_scan_top<<<1, 1024, 0, stream>>>(bsumE, nbE);
  k_scan_add<<<nbE, 256, 0, stream>>>(off_e, bsumE, E);
  k_scan_block<<<nbN, 256, 0, stream>>>(cnt_n, off_n, bsumN, N);
  k_scan_top<<<1, 1024, 0, stream>>>(bsumN, nbN);
  k_scan_add<<<nbN, 256, 0, stream>>>(off_n, bsumN, N);
  k_settail<<<1, 1, 0, stream>>>(off_e, E, off_n, N, M);
  k_fill<<<(M + 255) / 256, 256, 0, stream>>>(srcI, dstI, M, off_e, fill_e,
                                              csr_e, off_n, fill_n, csr_n);

  // ---- weight conversion ----
  k_wconv<<<128, 256, 0, stream>>>(Wa, Wa_t, 256, 128);
  k_wconv<<<128, 256, 0, stream>>>(Wb1, Wb1_t, 128, 256);
  k_wconv<<<128, 256, 0, stream>>>(Wb2, Wb2_t, 256, 128);
  k_wconv<<<128, 256, 0, stream>>>(Wl1, Wl1_t, 128, 256);
  k_wconv<<<128, 256, 0, stream>>>(Wl2, Wl2_t, 256, 128);

  // 1) gather1: lift only
  k_gather1<<<(E + 7) / 8, 256, 0, stream>>>(node_rep, off_e, csr_e, lift, E);

  // 2) Y1 = [lift|edge] @ Wa (+stats, +he)
  k_mfma_gemm_cat<<<dim3((E + 127) / 128), 256, 0, stream>>>(
      lift, edge_rep, Wa_t, eps2, sum_a, Y1, he, E);
  k_bnfin<<<1, 256, 0, stream>>>(sum_a, 128, E, ga, ba, st_a);

  // 3) gather2: lvl + hn
  k_gather2<<<(N + 15) / 16, 256, 0, stream>>>(Y1, st_a, node_rep, off_n,
                                               csr_n, eps1, hn, N);

  // 4) node path
  k_mfma_gemm<0><<<dim3((N + 127) / 128, 2), 256, 0, stream>>>(
      hn, Wb1_t, nullptr, sum_b1, Zn, N, 128, 256);
  k_bnfin<<<1, 256, 0, stream>>>(sum_b1, 256, N, gb1, bb1, st_b1);
  k_mfma_gemm<1><<<dim3((N + 127) / 128, 1), 256, 0, stream>>>(
      Zn, Wb2_t, st_b1, sum_b2, Y2n, N, 256, 128);
  k_bnfin<<<1, 256, 0, stream>>>(sum_b2, 128, N, gb2, bb2, st_b2);
  {
    long total = ((long)N * 128 + 7) / 8;
    k_bnrelu_out<<<(int)((total + 255) / 256), 256, 0, stream>>>(Y2n, st_b2, N,
                                                                 node_out);
  }

  // 5) edge path
  k_mfma_gemm<0><<<dim3((E + 127) / 128, 2), 256, 0, stream>>>(
      he, Wl1_t, nullptr, sum_l1, Ze, E, 128, 256);
  k_bnfin<<<1, 256, 0, stream>>>(sum_l1, 256, E, gl1, bl1, st_l1);
  k_mfma_gemm<1><<<dim3((E + 127) / 128, 1), 256, 0, stream>>>(
      Ze, Wl2_t, st_l1, sum_l2, Y2e, E, 256, 128);
  k_bnfin<<<1, 256, 0, stream>>>(sum_l2, 128, E, gl2, bl2, st_l2);
  {
    long total = ((long)E * 128 + 7) / 8;
    k_bnrelu_out<<<(int)((total + 255) / 256), 256, 0, stream>>>(Y2e, st_l2, E,
                                                                 edge_out);
  }
}